// Round 4
// baseline (65.886 us; speedup 1.0000x reference)
//
#include <hip/hip_runtime.h>

#define CURIOSITY_COEF 0.1f
#define EPS_F 1e-8f
#define ITERS 4

typedef float f32x4 __attribute__((ext_vector_type(4)));
typedef int   i32x4 __attribute__((ext_vector_type(4)));

// Quad-lane (aligned 4-lane cluster) exchanges via DPP quad_perm: pure VALU,
// no ds_bpermute / lgkmcnt on the critical path.
// xor1: [1,0,3,2] -> ctrl 0xB1 ; xor2: [2,3,0,1] -> ctrl 0x4E
__device__ __forceinline__ float fqxor1(float x) {
    return __int_as_float(__builtin_amdgcn_mov_dpp(__float_as_int(x), 0xB1, 0xF, 0xF, true));
}
__device__ __forceinline__ float fqxor2(float x) {
    return __int_as_float(__builtin_amdgcn_mov_dpp(__float_as_int(x), 0x4E, 0xF, 0xF, true));
}
__device__ __forceinline__ int iqxor1(int x) {
    return __builtin_amdgcn_mov_dpp(x, 0xB1, 0xF, 0xF, true);
}
__device__ __forceinline__ int iqxor2(int x) {
    return __builtin_amdgcn_mov_dpp(x, 0x4E, 0xF, 0xF, true);
}

// 4 lanes per group of 16; each lane owns one contiguous float4/int4 (16B),
// so every wave-level load/store covers a contiguous 4KB span. ITERS strided
// quarter-groups per thread: loads hoisted up front for MLP, 16x fewer
// workgroups than one-shot mapping.
__global__ __launch_bounds__(256) void srnd_kernel(
    const f32x4* __restrict__ r4,
    const i32x4* __restrict__ c4,
    f32x4*       __restrict__ o4,
    int Q)  // Q = number of quarter-groups = B*4
{
    int tid = blockIdx.x * blockDim.x + threadIdx.x;
    int S   = gridDim.x * blockDim.x;

    f32x4 rr[ITERS];
    i32x4 cc[ITERS];
    #pragma unroll
    for (int i = 0; i < ITERS; ++i) {
        int q = tid + i * S;
        if (q < Q) { rr[i] = r4[q]; cc[i] = c4[q]; }
    }

    #pragma unroll
    for (int i = 0; i < ITERS; ++i) {
        int q = tid + i * S;
        if (q >= Q) continue;

        float v[4]  = {rr[i].x, rr[i].y, rr[i].z, rr[i].w};
        int   cm[4] = {cc[i].x, cc[i].y, cc[i].z, cc[i].w};

        // Masked min accumulators; max tracked as min of negated values so
        // every accumulator uses the same +INF fill (cndmask with -v is one
        // instruction via VOP3 input modifier).
        float minC = INFINITY, nmxC = INFINITY;   // nmxC = -maxC
        float minI = INFINITY, nmxI = INFINITY;   // nmxI = -maxI
        int   cnt  = 0;
        #pragma unroll
        for (int e = 0; e < 4; ++e) {
            bool  c = (cm[e] != 0);
            float x = v[e];
            minC = fminf(minC, c ?  x : INFINITY);
            nmxC = fminf(nmxC, c ? -x : INFINITY);
            minI = fminf(minI, c ? INFINITY :  x);
            nmxI = fminf(nmxI, c ? INFINITY : -x);
            cnt += c ? 1 : 0;
        }

        // Quad butterfly via DPP (group = aligned 4-lane cluster).
        minC = fminf(minC, fqxor1(minC));
        nmxC = fminf(nmxC, fqxor1(nmxC));
        minI = fminf(minI, fqxor1(minI));
        nmxI = fminf(nmxI, fqxor1(nmxI));
        cnt += iqxor1(cnt);
        minC = fminf(minC, fqxor2(minC));
        nmxC = fminf(nmxC, fqxor2(nmxC));
        minI = fminf(minI, fqxor2(minI));
        nmxI = fminf(nmxI, fqxor2(nmxI));
        cnt += iqxor2(cnt);

        int cntC = cnt;
        int cntI = 16 - cnt;

        // out = sign * 0.1 * (r - min) * inv  ==  fma(r, a, b) with the sign,
        // scale, and min folded into per-stratum (a, b). v_rcp_f32 approx is
        // ~2^-22 rel err -> ~1e-8 abs on a 0.1-scaled output, far below tol.
        float dC   = -nmxC - minC + EPS_F;         // maxC - minC + eps
        float dI   = -nmxI - minI + EPS_F;
        float invC = __builtin_amdgcn_rcpf(dC);
        float invI = __builtin_amdgcn_rcpf(dI);
        float aC =  CURIOSITY_COEF * invC;
        float bC = -aC * minC;
        float aI = -CURIOSITY_COEF * invI;
        float bI = -aI * minI;
        // Singleton stratum: n = 0.5 exactly -> out = +/-0.05 exactly.
        if (cntC == 1) { aC = 0.0f; bC =  0.05f; }
        if (cntI == 1) { aI = 0.0f; bI = -0.05f; }
        // Empty stratum yields inf/nan in (a,b) but only on the side of the
        // cndmask an element never selects (its own stratum has count >= 1).

        f32x4 ov;
        #pragma unroll
        for (int e = 0; e < 4; ++e) {
            bool  c = (cm[e] != 0);
            float a = c ? aC : aI;
            float b = c ? bC : bI;
            ov[e] = fmaf(v[e], a, b);
        }

        // Output is never re-read: don't let it evict L3-resident inputs.
        __builtin_nontemporal_store(ov, &o4[q]);
    }
}

extern "C" void kernel_launch(void* const* d_in, const int* in_sizes, int n_in,
                              void* d_out, int out_size, void* d_ws, size_t ws_size,
                              hipStream_t stream) {
    const float* rewards = (const float*)d_in[0];
    const int*   corr    = (const int*)d_in[1];
    float*       out     = (float*)d_out;

    int N = in_sizes[0];
    int Q = N / 4;  // quarter-groups (group_size = 16 -> 4 lanes/group)

    const int threads = 256;
    const int blocks  = (Q + threads * ITERS - 1) / (threads * ITERS);
    srnd_kernel<<<blocks, threads, 0, stream>>>(
        reinterpret_cast<const f32x4*>(rewards),
        reinterpret_cast<const i32x4*>(corr),
        reinterpret_cast<f32x4*>(out), Q);
}

// Round 5
// 59.504 us; speedup vs baseline: 1.1072x; 1.1072x over previous
//
#include <hip/hip_runtime.h>

#define CURIOSITY_COEF 0.1f
#define EPS_F 1e-8f

typedef float f32x4 __attribute__((ext_vector_type(4)));
typedef int   i32x4 __attribute__((ext_vector_type(4)));

// Quad-lane (aligned 4-lane cluster) exchanges via DPP quad_perm: pure VALU,
// no ds_bpermute / lgkmcnt on the critical path.
// xor1: [1,0,3,2] -> ctrl 0xB1 ; xor2: [2,3,0,1] -> ctrl 0x4E
__device__ __forceinline__ float fqxor1(float x) {
    return __int_as_float(__builtin_amdgcn_mov_dpp(__float_as_int(x), 0xB1, 0xF, 0xF, true));
}
__device__ __forceinline__ float fqxor2(float x) {
    return __int_as_float(__builtin_amdgcn_mov_dpp(__float_as_int(x), 0x4E, 0xF, 0xF, true));
}
__device__ __forceinline__ int iqxor1(int x) {
    return __builtin_amdgcn_mov_dpp(x, 0xB1, 0xF, 0xF, true);
}
__device__ __forceinline__ int iqxor2(int x) {
    return __builtin_amdgcn_mov_dpp(x, 0x4E, 0xF, 0xF, true);
}

// 4 lanes per group of 16; each lane owns one contiguous float4/int4 (16B),
// so every wave-level load/store covers a contiguous 4KB span (max
// coalescing). ONE quarter-group per thread: VGPR stays ~20 so occupancy
// stays at the 8-waves/SIMD cap -- TLP, not ILP, hides the memory latency
// (R4's ITERS=4 batching cost 28 VGPR -> occupancy 71%->48% -> regression).
__global__ __launch_bounds__(256) void srnd_kernel(
    const f32x4* __restrict__ r4,
    const i32x4* __restrict__ c4,
    f32x4*       __restrict__ o4,
    int Q)  // Q = number of quarter-groups = B*4
{
    int q = blockIdx.x * blockDim.x + threadIdx.x;
    if (q >= Q) return;

    f32x4 rr = r4[q];
    i32x4 cc = c4[q];
    float v[4]  = {rr.x, rr.y, rr.z, rr.w};
    int   cm[4] = {cc.x, cc.y, cc.z, cc.w};

    // Masked min accumulators; max tracked as min of negated values so every
    // accumulator uses the same +INF fill (the -v comes free as a VOP3 input
    // modifier on the cndmask/min).
    float minC = INFINITY, nmxC = INFINITY;   // nmxC = -maxC
    float minI = INFINITY, nmxI = INFINITY;   // nmxI = -maxI
    int   cnt  = 0;
    #pragma unroll
    for (int e = 0; e < 4; ++e) {
        bool  c = (cm[e] != 0);
        float x = v[e];
        minC = fminf(minC, c ?  x : INFINITY);
        nmxC = fminf(nmxC, c ? -x : INFINITY);
        minI = fminf(minI, c ? INFINITY :  x);
        nmxI = fminf(nmxI, c ? INFINITY : -x);
        cnt += c ? 1 : 0;
    }

    // Quad butterfly via DPP (group = aligned 4-lane cluster).
    minC = fminf(minC, fqxor1(minC));
    nmxC = fminf(nmxC, fqxor1(nmxC));
    minI = fminf(minI, fqxor1(minI));
    nmxI = fminf(nmxI, fqxor1(nmxI));
    cnt += iqxor1(cnt);
    minC = fminf(minC, fqxor2(minC));
    nmxC = fminf(nmxC, fqxor2(nmxC));
    minI = fminf(minI, fqxor2(minI));
    nmxI = fminf(nmxI, fqxor2(nmxI));
    cnt += iqxor2(cnt);

    int cntC = cnt;
    int cntI = 16 - cnt;

    // out = sign * 0.1 * (r - min) * inv  ==  fma(r, a, b) with sign, scale,
    // and min folded into per-stratum (a, b). v_rcp_f32 rel err ~2^-22 ->
    // ~1e-8 abs on a 0.1-scaled output, far below the 2e-3 tolerance.
    float dC   = -nmxC - minC + EPS_F;         // maxC - minC + eps
    float dI   = -nmxI - minI + EPS_F;
    float invC = __builtin_amdgcn_rcpf(dC);
    float invI = __builtin_amdgcn_rcpf(dI);
    float aC =  CURIOSITY_COEF * invC;
    float bC = -aC * minC;
    float aI = -CURIOSITY_COEF * invI;
    float bI = -aI * minI;
    // Singleton stratum: n = 0.5 exactly -> out = +/-0.05 exactly.
    if (cntC == 1) { aC = 0.0f; bC =  0.05f; }
    if (cntI == 1) { aI = 0.0f; bI = -0.05f; }
    // Empty stratum yields inf/nan in (a,b) but only on the side of the
    // per-element select an element never takes (its own stratum count >= 1).

    f32x4 ov;
    #pragma unroll
    for (int e = 0; e < 4; ++e) {
        bool  c = (cm[e] != 0);
        float a = c ? aC : aI;
        float b = c ? bC : bI;
        ov[e] = fmaf(v[e], a, b);
    }

    // Output is never re-read: don't let it evict L3-resident inputs.
    __builtin_nontemporal_store(ov, &o4[q]);
}

extern "C" void kernel_launch(void* const* d_in, const int* in_sizes, int n_in,
                              void* d_out, int out_size, void* d_ws, size_t ws_size,
                              hipStream_t stream) {
    const float* rewards = (const float*)d_in[0];
    const int*   corr    = (const int*)d_in[1];
    float*       out     = (float*)d_out;

    int N = in_sizes[0];
    int Q = N / 4;  // quarter-groups (group_size = 16 -> 4 lanes/group)

    const int threads = 256;
    const int blocks  = (Q + threads - 1) / threads;
    srnd_kernel<<<blocks, threads, 0, stream>>>(
        reinterpret_cast<const f32x4*>(rewards),
        reinterpret_cast<const i32x4*>(corr),
        reinterpret_cast<f32x4*>(out), Q);
}